// Round 5
// baseline (1709.543 us; speedup 1.0000x reference)
//
#include <hip/hip_runtime.h>
#include <math.h>

// Problem constants
#define BB 64
#define NN 100
#define HH 128
#define T3 384

// Output layout (floats, concatenated in return order)
#define O0 0            // sample_logprob [64,99]
#define O1 6336         // sample_distance [64,1]
#define O2 6400         // greedy_distance [64,1]
#define O3 6464         // predict_matrix [64,100,100,2]
#define O4 1286464      // greedy_solution_matrix [64,100,100]

#define TINYF 1.17549435e-38f
#define SCALEF 0.08838834764831845f

// ---------------- threefry2x32 (exact JAX implementation) ----------------
__device__ __forceinline__ unsigned rotl32(unsigned x, int d) {
    return (x << d) | (x >> (32 - d));
}

__device__ __forceinline__ void tf2x32(unsigned ks0, unsigned ks1,
                                       unsigned x0, unsigned x1,
                                       unsigned& o0, unsigned& o1) {
    unsigned ks2 = ks0 ^ ks1 ^ 0x1BD11BDAu;
    x0 += ks0; x1 += ks1;
    x0 += x1; x1 = rotl32(x1, 13); x1 ^= x0;
    x0 += x1; x1 = rotl32(x1, 15); x1 ^= x0;
    x0 += x1; x1 = rotl32(x1, 26); x1 ^= x0;
    x0 += x1; x1 = rotl32(x1, 6);  x1 ^= x0;
    x0 += ks1; x1 += ks2 + 1u;
    x0 += x1; x1 = rotl32(x1, 17); x1 ^= x0;
    x0 += x1; x1 = rotl32(x1, 29); x1 ^= x0;
    x0 += x1; x1 = rotl32(x1, 16); x1 ^= x0;
    x0 += x1; x1 = rotl32(x1, 24); x1 ^= x0;
    x0 += ks2; x1 += ks0 + 2u;
    x0 += x1; x1 = rotl32(x1, 13); x1 ^= x0;
    x0 += x1; x1 = rotl32(x1, 15); x1 ^= x0;
    x0 += x1; x1 = rotl32(x1, 26); x1 ^= x0;
    x0 += x1; x1 = rotl32(x1, 6);  x1 ^= x0;
    x0 += ks0; x1 += ks1 + 3u;
    x0 += x1; x1 = rotl32(x1, 17); x1 ^= x0;
    x0 += x1; x1 = rotl32(x1, 29); x1 ^= x0;
    x0 += x1; x1 = rotl32(x1, 16); x1 ^= x0;
    x0 += x1; x1 = rotl32(x1, 24); x1 ^= x0;
    x0 += ks1; x1 += ks2 + 4u;
    x0 += x1; x1 = rotl32(x1, 13); x1 ^= x0;
    x0 += x1; x1 = rotl32(x1, 15); x1 ^= x0;
    x0 += x1; x1 = rotl32(x1, 26); x1 ^= x0;
    x0 += x1; x1 = rotl32(x1, 6);  x1 ^= x0;
    x0 += ks2; x1 += ks0 + 5u;
    o0 = x0; o1 = x1;
}

__device__ __forceinline__ float gumbel_f(unsigned k0, unsigned k1, unsigned f) {
    unsigned o0, o1;
    tf2x32(k0, k1, 0u, f, o0, o1);
    unsigned bits = o0 ^ o1;
    float u01 = __uint_as_float((bits >> 9) | 0x3F800000u) - 1.0f;
    float u = fmaxf(TINYF, u01 * (1.0f - TINYF) + TINYF);
    return -logf(-logf(u));
}

// ---------------- encoder kernels ----------------

__global__ void k_embed(const float* __restrict__ node, const float* __restrict__ demand,
                        const float* __restrict__ Wn0, const float* __restrict__ bn0,
                        float* __restrict__ h) {
    int idx = blockIdx.x * 256 + threadIdx.x;
    if (idx >= BB * NN * HH) return;
    int r = idx >> 7, c = idx & 127;
    float v = node[r * 2] * Wn0[c] + node[r * 2 + 1] * Wn0[128 + c]
            + demand[r] * Wn0[256 + c] + bn0[c];
    h[idx] = fmaxf(v, 0.0f);
}

__global__ void k_adj(const float* __restrict__ dis, float* __restrict__ A) {
    int row = blockIdx.x;
    const float* d = dis + row * NN;
    int l = threadIdx.x;
    float v0 = (l < NN) ? -d[l] : -__builtin_inff();
    float v1 = (l + 64 < NN) ? -d[l + 64] : -__builtin_inff();
    float m = fmaxf(v0, v1);
    for (int off = 32; off > 0; off >>= 1) m = fmaxf(m, __shfl_xor(m, off));
    float e0 = (l < NN) ? expf(v0 - m) : 0.0f;
    float e1 = (l + 64 < NN) ? expf(v1 - m) : 0.0f;
    float s = e0 + e1;
    for (int off = 32; off > 0; off >>= 1) s += __shfl_xor(s, off);
    float inv = 1.0f / s;
    if (l < NN) A[row * NN + l] = e0 * inv;
    if (l + 64 < NN) A[row * NN + l + 64] = e1 * inv;
}

// out[6400x128] = h[6400x128] @ W[128x128]
__global__ void k_hw(const float* __restrict__ h, const float* __restrict__ W,
                     float* __restrict__ out) {
    __shared__ float hs[8 * 128];
    int block_row = blockIdx.x * 8;
    int tid = threadIdx.x;
    int col = tid & 127;
    int rg = tid >> 7;
    for (int i = tid; i < 8 * 128; i += 256) hs[i] = h[block_row * 128 + i];
    __syncthreads();
    float acc[4] = {0.f, 0.f, 0.f, 0.f};
    for (int k = 0; k < 128; k++) {
        float w = W[k * 128 + col];
#pragma unroll
        for (int r = 0; r < 4; r++) acc[r] += hs[(rg + 2 * r) * 128 + k] * w;
    }
#pragma unroll
    for (int r = 0; r < 4; r++)
        out[(block_row + rg + 2 * r) * 128 + col] = acc[r];
}

// out[6400x384] = h[6400x128] @ W[128x384] + bias[384]
__global__ void k_mm384(const float* __restrict__ h, const float* __restrict__ W,
                        const float* __restrict__ bias, float* __restrict__ out) {
    __shared__ float hs[8 * 128];
    int block_row = blockIdx.x * 8;
    int tid = threadIdx.x;
    int col = blockIdx.y * 128 + (tid & 127);
    int rg = tid >> 7;
    for (int i = tid; i < 8 * 128; i += 256) hs[i] = h[block_row * 128 + i];
    __syncthreads();
    float acc[4] = {0.f, 0.f, 0.f, 0.f};
    for (int k = 0; k < 128; k++) {
        float w = W[k * 384 + col];
#pragma unroll
        for (int r = 0; r < 4; r++) acc[r] += hs[(rg + 2 * r) * 128 + k] * w;
    }
    float b = bias[col];
#pragma unroll
    for (int r = 0; r < 4; r++)
        out[(block_row + rg + 2 * r) * 384 + col] = acc[r] + b;
}

__global__ void k_transpose128(const float* __restrict__ Wq, float* __restrict__ WqT) {
    int i = blockIdx.x * 256 + threadIdx.x;
    if (i >= 128 * 128) return;
    int k = i >> 7, c = i & 127;
    WqT[k * 128 + c] = Wq[c * 128 + k];
}

__global__ void k_agg(const float* __restrict__ h, const float* __restrict__ Ws,
                      const float* __restrict__ A, const float* __restrict__ hw,
                      float* __restrict__ out) {
    __shared__ float hs[4 * 128];
    __shared__ float As[4 * 100];
    int b = blockIdx.x / 25;
    int i0 = (blockIdx.x % 25) * 4;
    int tid = threadIdx.x;
    int col = tid & 127;
    int rg = tid >> 7;
    int rowbase = b * NN + i0;
    for (int idx = tid; idx < 4 * 128; idx += 256) hs[idx] = h[rowbase * 128 + idx];
    for (int idx = tid; idx < 4 * 100; idx += 256) As[idx] = A[rowbase * 100 + idx];
    __syncthreads();
    float acc0 = 0.f, acc1 = 0.f;
    for (int k = 0; k < 128; k++) {
        float w = Ws[k * 128 + col];
        acc0 += hs[rg * 128 + k] * w;
        acc1 += hs[(rg + 2) * 128 + k] * w;
    }
    const float* hwb = hw + b * NN * 128;
    for (int j = 0; j < NN; j++) {
        float v = hwb[j * 128 + col];
        acc0 += As[rg * 100 + j] * v;
        acc1 += As[(rg + 2) * 100 + j] * v;
    }
    out[(rowbase + rg) * 128 + col]     = fmaxf(acc0, 0.0f);
    out[(rowbase + rg + 2) * 128 + col] = fmaxf(acc1, 0.0f);
}

__global__ void k_predict(const float* __restrict__ dis, const float* __restrict__ We,
                          const float* __restrict__ be, const float* __restrict__ Wc,
                          const float* __restrict__ bc, float* __restrict__ out3) {
    __shared__ float sWe[128], sbe[128], sc0[128], sc1[128];
    int tid = threadIdx.x;
    if (tid < 128) {
        sWe[tid] = We[tid];
        sbe[tid] = be[tid];
        sc0[tid] = Wc[tid * 2];
        sc1[tid] = Wc[tid * 2 + 1];
    }
    __syncthreads();
    float b0 = bc[0], b1 = bc[1];
    for (int pos = blockIdx.x * 256 + tid; pos < BB * NN * NN; pos += gridDim.x * 256) {
        float d = dis[pos];
        float a0 = b0, a1 = b1;
        for (int k = 0; k < 128; k++) {
            float e = fmaxf(d * sWe[k] + sbe[k], 0.0f);
            a0 += e * sc0[k];
            a1 += e * sc1[k];
        }
        float m = fmaxf(a0, a1);
        float p0 = expf(a0 - m), p1 = expf(a1 - m);
        float inv = 1.0f / (p0 + p1);
        out3[pos * 2]     = p0 * inv;
        out3[pos * 2 + 1] = p1 * inv;
    }
}

__global__ void k_zero(float* __restrict__ p, int n) {
    int i = blockIdx.x * 256 + threadIdx.x;
    if (i < n) p[i] = 0.0f;
}

// ---------------- decoder v5: register-resident Whh0/Whh1, stream only Wih1 -----------
// 64 blocks x 512 threads (8 waves, 1 block/CU). Thread (kg=tid>>6, jg=tid&63)
// owns a 16k x 6j tile of each Whh matrix in registers (192 VGPRs of weights).
// Per step only Wih1 (196 KB) is streamed from L2 -> ~3x less VMEM than v4.
__global__ __launch_bounds__(512, 2) void k_decode5(
    const float* __restrict__ P0,       // [6400, 384]  x@Wih0 + bih0
    const float* __restrict__ Z,        // [6400, 128]  x@Wq^T
    const float* __restrict__ dis,
    const float* __restrict__ Wih,      // [2,128,384]
    const float* __restrict__ Whh,      // [2,128,384]
    const float* __restrict__ bih,
    const float* __restrict__ bhh,
    float* __restrict__ out) {
    __shared__ float Zs[NN * 132];          // 52.8 KB
    __shared__ float h0s[2 * 132], h1s[2 * 132];
    __shared__ float gi0s[2 * 384];
    __shared__ float pgA[8 * 2 * 392];      // gh0 partials; reused for gi1 after phase B
    __shared__ float pgB[8 * 2 * 392];      // gh1 partials (live until phase D)
    __shared__ float sbhh0[T3], sbih1[T3], sbhh1[T3];
    __shared__ float pl[2 * 2 * 100];       // [m][ks][n]
    __shared__ float gum[128];
    __shared__ int s_ind2[2];

    const int tid = threadIdx.x;
    const int b = blockIdx.x;
    const int kg = tid >> 6;            // 0..7 -> k0 = kg*16
    const int jg = tid & 63;            // 0..63 -> j0 = jg*6
    const int k0 = kg * 16, j0 = jg * 6;

    const float* __restrict__ Wih1 = Wih + 128 * T3;

    // ---- load register weight tiles (Whh0, Whh1) ----
    float wA[16][6], wB[16][6];
    {
        const float* WAp = Whh + (size_t)k0 * T3 + j0;
        const float* WBp = Whh + 128 * T3 + (size_t)k0 * T3 + j0;
#pragma unroll
        for (int k = 0; k < 16; k++) {
#pragma unroll
            for (int q = 0; q < 3; q++) {
                float2 a = *(const float2*)(WAp + (size_t)k * T3 + 2 * q);
                wA[k][2 * q] = a.x; wA[k][2 * q + 1] = a.y;
                float2 c = *(const float2*)(WBp + (size_t)k * T3 + 2 * q);
                wB[k][2 * q] = c.x; wB[k][2 * q + 1] = c.y;
            }
        }
    }

    // ---- static staging ----
    for (int i4 = tid; i4 < NN * 32; i4 += 512) {
        int r = i4 >> 5, c4 = (i4 & 31) * 4;
        *(float4*)&Zs[r * 132 + c4] = *(const float4*)&Z[(b * NN + r) * 128 + c4];
    }
    if (tid < T3) {
        sbhh0[tid] = bhh[tid];
        sbih1[tid] = bih[T3 + tid];
        sbhh1[tid] = bhh[T3 + tid];
    }
    if (tid < 256) {
        int m = tid >> 7, i = tid & 127;
        h0s[m * 132 + i] = 0.0f;
        h1s[m * 132 + i] = 0.0f;
    }
    if (tid == 0) { s_ind2[0] = 0; s_ind2[1] = 0; }

    unsigned kk0, kk1;
    tf2x32(0u, 42u, 0u, 0u, kk0, kk1);   // k1 of split(key(42))

    int lastm = 0;       // tracked by tid<128 (selection threads)
    float dist = 0.0f;
    __syncthreads();

    for (int t = 0; t < NN - 1; t++) {
        // ---- RNG chain advance (uniform, all threads) ----
        unsigned sk0, sk1, nkA, nkB;
        tf2x32(kk0, kk1, 0u, 1u, sk0, sk1);
        tf2x32(kk0, kk1, 0u, 0u, nkA, nkB);
        kk0 = nkA; kk1 = nkB;

        // ---- gi0 prefetch (row of P0 per mode) into registers ----
        float pf0 = 0.f, pf1 = 0.f;
        int pf_m = 0, pf_j = 0;
        if (tid < 384) {
            pf_m = (tid >= 192);
            pf_j = (tid - pf_m * 192) * 2;
            float2 g2 = *(const float2*)&P0[(size_t)(b * NN + s_ind2[pf_m]) * T3 + pf_j];
            pf0 = g2.x; pf1 = g2.y;
        }

        // ===== phase A: gh0 (reg wA) and gh1 (reg wB) partials =====
        {
            float acc0[6], acc1[6];
#pragma unroll
            for (int j = 0; j < 6; j++) { acc0[j] = 0.f; acc1[j] = 0.f; }
#pragma unroll
            for (int q = 0; q < 4; q++) {
                float4 ha = *(const float4*)&h0s[k0 + 4 * q];
                float4 hb = *(const float4*)&h0s[132 + k0 + 4 * q];
#pragma unroll
                for (int j = 0; j < 6; j++) {
                    acc0[j] += wA[4 * q + 0][j] * ha.x + wA[4 * q + 1][j] * ha.y
                             + wA[4 * q + 2][j] * ha.z + wA[4 * q + 3][j] * ha.w;
                    acc1[j] += wA[4 * q + 0][j] * hb.x + wA[4 * q + 1][j] * hb.y
                             + wA[4 * q + 2][j] * hb.z + wA[4 * q + 3][j] * hb.w;
                }
            }
#pragma unroll
            for (int q = 0; q < 3; q++) {
                float2 o0; o0.x = acc0[2 * q]; o0.y = acc0[2 * q + 1];
                *(float2*)&pgA[(kg * 2 + 0) * 392 + j0 + 2 * q] = o0;
                float2 o1; o1.x = acc1[2 * q]; o1.y = acc1[2 * q + 1];
                *(float2*)&pgA[(kg * 2 + 1) * 392 + j0 + 2 * q] = o1;
            }
        }
        {
            float acc0[6], acc1[6];
#pragma unroll
            for (int j = 0; j < 6; j++) { acc0[j] = 0.f; acc1[j] = 0.f; }
#pragma unroll
            for (int q = 0; q < 4; q++) {
                float4 ha = *(const float4*)&h1s[k0 + 4 * q];
                float4 hb = *(const float4*)&h1s[132 + k0 + 4 * q];
#pragma unroll
                for (int j = 0; j < 6; j++) {
                    acc0[j] += wB[4 * q + 0][j] * ha.x + wB[4 * q + 1][j] * ha.y
                             + wB[4 * q + 2][j] * ha.z + wB[4 * q + 3][j] * ha.w;
                    acc1[j] += wB[4 * q + 0][j] * hb.x + wB[4 * q + 1][j] * hb.y
                             + wB[4 * q + 2][j] * hb.z + wB[4 * q + 3][j] * hb.w;
                }
            }
#pragma unroll
            for (int q = 0; q < 3; q++) {
                float2 o0; o0.x = acc0[2 * q]; o0.y = acc0[2 * q + 1];
                *(float2*)&pgB[(kg * 2 + 0) * 392 + j0 + 2 * q] = o0;
                float2 o1; o1.x = acc1[2 * q]; o1.y = acc1[2 * q + 1];
                *(float2*)&pgB[(kg * 2 + 1) * 392 + j0 + 2 * q] = o1;
            }
        }
        if (tid < 384) {
            gi0s[pf_m * 384 + pf_j] = pf0;
            gi0s[pf_m * 384 + pf_j + 1] = pf1;
        }
        __syncthreads();

        // ===== phase B: h0 update (256 thr) =====
        if (tid < 256) {
            int m = tid >> 7, i = tid & 127;
            float ghr = sbhh0[i], ghz = sbhh0[i + 128], ghn = sbhh0[i + 256];
#pragma unroll
            for (int g = 0; g < 8; g++) {
                int pb = (g * 2 + m) * 392;
                ghr += pgA[pb + i];
                ghz += pgA[pb + i + 128];
                ghn += pgA[pb + i + 256];
            }
            float rr = 1.0f / (1.0f + expf(-(gi0s[m * 384 + i] + ghr)));
            float zz = 1.0f / (1.0f + expf(-(gi0s[m * 384 + i + 128] + ghz)));
            float nn = tanhf(gi0s[m * 384 + i + 256] + rr * ghn);
            h0s[m * 132 + i] = (1.0f - zz) * nn + zz * h0s[m * 132 + i];
        }
        __syncthreads();

        // ===== phase C: gi1 partials (streamed Wih1, all 512 thr) =====
        {
            float acc0[6], acc1[6];
#pragma unroll
            for (int j = 0; j < 6; j++) { acc0[j] = 0.f; acc1[j] = 0.f; }
#pragma unroll
            for (int q = 0; q < 4; q++) {
                float4 ha = *(const float4*)&h0s[k0 + 4 * q];
                float4 hb = *(const float4*)&h0s[132 + k0 + 4 * q];
#pragma unroll
                for (int kk2 = 0; kk2 < 4; kk2++) {
                    const float* wp = Wih1 + (size_t)(k0 + 4 * q + kk2) * T3 + j0;
                    float2 w01 = *(const float2*)(wp);
                    float2 w23 = *(const float2*)(wp + 2);
                    float2 w45 = *(const float2*)(wp + 4);
                    float hx = (kk2 == 0) ? ha.x : (kk2 == 1) ? ha.y : (kk2 == 2) ? ha.z : ha.w;
                    float hy = (kk2 == 0) ? hb.x : (kk2 == 1) ? hb.y : (kk2 == 2) ? hb.z : hb.w;
                    acc0[0] += w01.x * hx; acc0[1] += w01.y * hx;
                    acc0[2] += w23.x * hx; acc0[3] += w23.y * hx;
                    acc0[4] += w45.x * hx; acc0[5] += w45.y * hx;
                    acc1[0] += w01.x * hy; acc1[1] += w01.y * hy;
                    acc1[2] += w23.x * hy; acc1[3] += w23.y * hy;
                    acc1[4] += w45.x * hy; acc1[5] += w45.y * hy;
                }
            }
#pragma unroll
            for (int q = 0; q < 3; q++) {
                float2 o0; o0.x = acc0[2 * q]; o0.y = acc0[2 * q + 1];
                *(float2*)&pgA[(kg * 2 + 0) * 392 + j0 + 2 * q] = o0;
                float2 o1; o1.x = acc1[2 * q]; o1.y = acc1[2 * q + 1];
                *(float2*)&pgA[(kg * 2 + 1) * 392 + j0 + 2 * q] = o1;
            }
        }
        __syncthreads();

        // ===== phase D: h1 update (256 thr) =====
        if (tid < 256) {
            int m = tid >> 7, i = tid & 127;
            float gir = sbih1[i], giz = sbih1[i + 128], gin = sbih1[i + 256];
            float ghr = sbhh1[i], ghz = sbhh1[i + 128], ghn = sbhh1[i + 256];
#pragma unroll
            for (int g = 0; g < 8; g++) {
                int pa = (g * 2 + m) * 392;
                gir += pgA[pa + i];
                giz += pgA[pa + i + 128];
                gin += pgA[pa + i + 256];
                ghr += pgB[pa + i];
                ghz += pgB[pa + i + 128];
                ghn += pgB[pa + i + 256];
            }
            float rr = 1.0f / (1.0f + expf(-(gir + ghr)));
            float zz = 1.0f / (1.0f + expf(-(giz + ghz)));
            float nn = tanhf(gin + rr * ghn);
            h1s[m * 132 + i] = (1.0f - zz) * nn + zz * h1s[m * 132 + i];
        }
        __syncthreads();

        // ===== phase E: logits partials (200 thr) + gumbel (thr 256..355) =====
        if (tid < 200) {
            int ks = tid / 100, n = tid - ks * 100;
            int kk0p = ks * 64;
            const float* Zp = &Zs[n * 132 + kk0p];
            const float* hp = &h1s[kk0p];
            float a0 = 0.f, a1 = 0.f;
#pragma unroll 4
            for (int q = 0; q < 16; q++) {
                float4 z4 = *(const float4*)(Zp + 4 * q);
                float4 hA = *(const float4*)(hp + 4 * q);
                float4 hB = *(const float4*)(hp + 132 + 4 * q);
                a0 += hA.x * z4.x; a0 += hA.y * z4.y; a0 += hA.z * z4.z; a0 += hA.w * z4.w;
                a1 += hB.x * z4.x; a1 += hB.y * z4.y; a1 += hB.z * z4.z; a1 += hB.w * z4.w;
            }
            pl[(0 * 2 + ks) * 100 + n] = a0;
            pl[(1 * 2 + ks) * 100 + n] = a1;
        } else if (tid >= 256 && tid < 356) {
            int u = tid - 256;
            gum[u] = gumbel_f(sk0, sk1, (unsigned)(b * NN + u));
        }
        __syncthreads();

        // ===== phase F: softmax stats + selection (wave0: sample, wave1: greedy) =====
        if (tid < 128) {
            const int m = tid >> 6, lane = tid & 63;
            float v0, v1 = -__builtin_inff();
            v0 = (pl[(m * 2 + 0) * 100 + lane] + pl[(m * 2 + 1) * 100 + lane]) * SCALEF;
            if (lane + 64 < NN)
                v1 = (pl[(m * 2 + 0) * 100 + lane + 64] + pl[(m * 2 + 1) * 100 + lane + 64]) * SCALEF;
            float mx = fmaxf(v0, v1);
            for (int off = 32; off > 0; off >>= 1) mx = fmaxf(mx, __shfl_xor(mx, off));
            float e = expf(v0 - mx) + ((lane + 64 < NN) ? expf(v1 - mx) : 0.0f);
            for (int off = 32; off > 0; off >>= 1) e += __shfl_xor(e, off);
            float a0 = v0, a1 = v1;
            if (m == 0) {
                a0 += gum[lane];
                if (lane + 64 < NN) a1 += gum[lane + 64];
            }
            float bv; int bi;
            if (a1 > a0) { bv = a1; bi = lane + 64; } else { bv = a0; bi = lane; }
            for (int off = 32; off > 0; off >>= 1) {
                float ov = __shfl_xor(bv, off);
                int   oi = __shfl_xor(bi, off);
                if (ov > bv || (ov == bv && oi < bi)) { bv = ov; bi = oi; }
            }
            int ind = bi;
            float la = __shfl(v0, ind & 63);
            float lb = __shfl(v1, ind & 63);
            float lv = (ind < 64) ? la : lb;
            if (lane == 0) {
                if (m == 0) out[O0 + b * (NN - 1) + t] = lv - mx - logf(e);
                else        out[O4 + (size_t)b * NN * NN + lastm * NN + ind] = 1.0f;
                s_ind2[m] = ind;
            }
            dist += dis[b * NN * NN + lastm * NN + ind];
            lastm = ind;
        }
        __syncthreads();
    }

    if (tid == 0)  out[O1 + b] = dist;
    if (tid == 64) out[O2 + b] = dist;
}

// ---------------- fallback decoder (round-2 verified, small ws) ----------------
__global__ __launch_bounds__(768) void k_decode2(
    const float* __restrict__ P0, const float* __restrict__ Z,
    const float* __restrict__ dis,
    const float* __restrict__ Wih, const float* __restrict__ Whh,
    const float* __restrict__ bih, const float* __restrict__ bhh,
    float* __restrict__ out) {
    __shared__ float Zs[NN * 129];
    __shared__ float h0s[128], h1s[128];
    __shared__ float gi0s[T3];
    __shared__ float pg0[2 * T3];
    __shared__ float gi1s[T3], gh1s[T3];
    __shared__ float sbhh0[T3], sbih1[T3], sbhh1[T3];
    __shared__ float plx[4 * NN];
    __shared__ float logits[NN];
    __shared__ float s_m, s_s;
    __shared__ int s_ind;

    const int tid = threadIdx.x;
    const int b = blockIdx.x >> 1;
    const int greedy = blockIdx.x & 1;

    const float* Whh0 = Whh;
    const float* Wih1 = Wih + 128 * T3;
    const float* Whh1 = Whh + 128 * T3;

    for (int idx = tid; idx < NN * 128; idx += 768) {
        int r = idx >> 7, c = idx & 127;
        Zs[r * 129 + c] = Z[(b * NN + r) * 128 + c];
    }
    if (tid < T3) {
        sbhh0[tid] = bhh[tid];
        sbih1[tid] = bih[T3 + tid];
        sbhh1[tid] = bhh[T3 + tid];
    }
    if (tid < 128) { h0s[tid] = 0.0f; h1s[tid] = 0.0f; }

    unsigned kk0, kk1;
    tf2x32(0u, 42u, 0u, 0u, kk0, kk1);

    int last = 0;
    float dist = 0.0f;
    __syncthreads();

    for (int t = 0; t < NN - 1; t++) {
        unsigned sk0, sk1, nk0, nk1;
        tf2x32(kk0, kk1, 0u, 1u, sk0, sk1);
        tf2x32(kk0, kk1, 0u, 0u, nk0, nk1);
        kk0 = nk0; kk1 = nk1;

        {
            const float* P0row = P0 + (size_t)(b * NN + last) * T3;
            if (tid < T3) {
                int j = tid;
                float acc = 0.0f;
                for (int k = 0; k < 64; k++) acc += h0s[k] * Whh0[k * T3 + j];
                pg0[j] = acc;
                gi0s[j] = P0row[j];
            } else {
                int j = tid - T3;
                float acc = 0.0f;
                for (int k = 64; k < 128; k++) acc += h0s[k] * Whh0[k * T3 + j];
                pg0[T3 + j] = acc;
            }
        }
        __syncthreads();
        if (tid < 128) {
            float ghr = pg0[tid] + pg0[T3 + tid] + sbhh0[tid];
            float ghz = pg0[tid + 128] + pg0[T3 + tid + 128] + sbhh0[tid + 128];
            float ghn = pg0[tid + 256] + pg0[T3 + tid + 256] + sbhh0[tid + 256];
            float r = 1.0f / (1.0f + expf(-(gi0s[tid] + ghr)));
            float z = 1.0f / (1.0f + expf(-(gi0s[tid + 128] + ghz)));
            float n = tanhf(gi0s[tid + 256] + r * ghn);
            h0s[tid] = (1.0f - z) * n + z * h0s[tid];
        }
        __syncthreads();
        if (tid < T3) {
            int j = tid;
            float acc = sbih1[j];
            for (int k = 0; k < 128; k++) acc += h0s[k] * Wih1[k * T3 + j];
            gi1s[j] = acc;
        } else {
            int j = tid - T3;
            float acc = sbhh1[j];
            for (int k = 0; k < 128; k++) acc += h1s[k] * Whh1[k * T3 + j];
            gh1s[j] = acc;
        }
        __syncthreads();
        if (tid < 128) {
            float r = 1.0f / (1.0f + expf(-(gi1s[tid] + gh1s[tid])));
            float z = 1.0f / (1.0f + expf(-(gi1s[tid + 128] + gh1s[tid + 128])));
            float n = tanhf(gi1s[tid + 256] + r * gh1s[tid + 256]);
            h1s[tid] = (1.0f - z) * n + z * h1s[tid];
        }
        __syncthreads();
        if (tid < 400) {
            int n = tid % 100, p = tid / 100;
            int k0 = p * 32;
            float acc = 0.0f;
            for (int kk = 0; kk < 32; kk++) acc += h1s[k0 + kk] * Zs[n * 129 + k0 + kk];
            plx[p * 100 + n] = acc;
        }
        __syncthreads();
        if (tid < 64) {
            float v0 = -__builtin_inff(), v1 = -__builtin_inff();
            {
                int n = tid;
                v0 = (plx[n] + plx[100 + n] + plx[200 + n] + plx[300 + n]) * SCALEF;
                logits[n] = v0;
            }
            if (tid + 64 < NN) {
                int n = tid + 64;
                v1 = (plx[n] + plx[100 + n] + plx[200 + n] + plx[300 + n]) * SCALEF;
                logits[n] = v1;
            }
            float m = fmaxf(v0, v1);
            for (int off = 32; off > 0; off >>= 1) m = fmaxf(m, __shfl_xor(m, off));
            float e = expf(v0 - m) + ((tid + 64 < NN) ? expf(v1 - m) : 0.0f);
            for (int off = 32; off > 0; off >>= 1) e += __shfl_xor(e, off);
            float a0 = v0, a1 = v1;
            if (!greedy) {
                a0 = v0 + gumbel_f(sk0, sk1, (unsigned)(b * NN + tid));
                if (tid + 64 < NN) a1 = v1 + gumbel_f(sk0, sk1, (unsigned)(b * NN + tid + 64));
            }
            float bv; int bi;
            if (a1 > a0) { bv = a1; bi = tid + 64; } else { bv = a0; bi = tid; }
            for (int off = 32; off > 0; off >>= 1) {
                float ov = __shfl_xor(bv, off);
                int   oi = __shfl_xor(bi, off);
                if (ov > bv || (ov == bv && oi < bi)) { bv = ov; bi = oi; }
            }
            if (tid == 0) { s_m = m; s_s = e; s_ind = bi; }
        }
        __syncthreads();
        int ind = s_ind;
        if (tid == 0) {
            if (!greedy) out[O0 + b * (NN - 1) + t] = logits[ind] - s_m - logf(s_s);
            dist += dis[b * NN * NN + last * NN + ind];
            if (greedy) out[O4 + b * NN * NN + last * NN + ind] = 1.0f;
        }
        last = ind;
        __syncthreads();
    }
    if (tid == 0) {
        if (!greedy) out[O1 + b] = dist;
        else         out[O2 + b] = dist;
    }
}

// ---------------- host launcher ----------------
extern "C" void kernel_launch(void* const* d_in, const int* in_sizes, int n_in,
                              void* d_out, int out_size, void* d_ws, size_t ws_size,
                              hipStream_t stream) {
    (void)in_sizes; (void)n_in; (void)out_size;
    const float* node   = (const float*)d_in[0];
    const float* demand = (const float*)d_in[1];
    const float* dis    = (const float*)d_in[2];
    const float* Wn0    = (const float*)d_in[3];
    const float* bn0    = (const float*)d_in[4];
    const float* Ws     = (const float*)d_in[5];
    const float* Wngh   = (const float*)d_in[6];
    const float* We     = (const float*)d_in[7];
    const float* be     = (const float*)d_in[8];
    const float* Wih    = (const float*)d_in[9];
    const float* Whh    = (const float*)d_in[10];
    const float* bih    = (const float*)d_in[11];
    const float* bhh    = (const float*)d_in[12];
    const float* Wq     = (const float*)d_in[13];
    const float* Wc     = (const float*)d_in[14];
    const float* bc     = (const float*)d_in[15];
    float* out = (float*)d_out;
    float* ws  = (float*)d_ws;

    float* hA  = ws;
    float* hB  = ws + 819200;
    float* hw  = ws + 1638400;      // hw during encoder; Z after
    float* A   = ws + 2457600;
    float* P0  = ws + 2457600;      // overlays A after encoder
    float* WqT = ws + 4915200;
    const size_t need_bytes = (size_t)4931584 * 4;
    const bool big_ws = ws_size >= need_bytes;

    hipLaunchKernelGGL(k_embed, dim3(3200), dim3(256), 0, stream, node, demand, Wn0, bn0, hA);
    hipLaunchKernelGGL(k_adj, dim3(6400), dim3(64), 0, stream, dis, A);

    float* cur = hA;
    float* nxt = hB;
    for (int l = 0; l < 3; l++) {
        hipLaunchKernelGGL(k_hw, dim3(800), dim3(256), 0, stream, cur, Wngh + l * 16384, hw);
        hipLaunchKernelGGL(k_agg, dim3(1600), dim3(256), 0, stream, cur, Ws + l * 16384, A, hw, nxt);
        float* tswap = cur; cur = nxt; nxt = tswap;
    }

    hipLaunchKernelGGL(k_predict, dim3(2500), dim3(256), 0, stream, dis, We, be, Wc, bc, out + O3);
    hipLaunchKernelGGL(k_zero, dim3(2500), dim3(256), 0, stream, out + O4, BB * NN * NN);

    hipLaunchKernelGGL(k_transpose128, dim3(64), dim3(256), 0, stream, Wq, WqT);
    hipLaunchKernelGGL(k_hw, dim3(800), dim3(256), 0, stream, cur, WqT, hw);   // Z
    hipLaunchKernelGGL(k_mm384, dim3(800, 3), dim3(256), 0, stream, cur, Wih, bih, P0);
    if (big_ws) {
        hipLaunchKernelGGL(k_decode5, dim3(64), dim3(512), 0, stream,
                           P0, hw, dis, Wih, Whh, bih, bhh, out);
    } else {
        hipLaunchKernelGGL(k_decode2, dim3(128), dim3(768), 0, stream,
                           P0, hw, dis, Wih, Whh, bih, bhh, out);
    }
}

// Round 6
// 1695.603 us; speedup vs baseline: 1.0082x; 1.0082x over previous
//
#include <hip/hip_runtime.h>
#include <math.h>

// Problem constants
#define BB 64
#define NN 100
#define HH 128
#define T3 384

// Output layout (floats, concatenated in return order)
#define O0 0            // sample_logprob [64,99]
#define O1 6336         // sample_distance [64,1]
#define O2 6400         // greedy_distance [64,1]
#define O3 6464         // predict_matrix [64,100,100,2]
#define O4 1286464      // greedy_solution_matrix [64,100,100]

#define TINYF 1.17549435e-38f
#define SCALEF 0.08838834764831845f

// ---------------- threefry2x32 (exact JAX implementation) ----------------
__device__ __forceinline__ unsigned rotl32(unsigned x, int d) {
    return (x << d) | (x >> (32 - d));
}

__device__ __forceinline__ void tf2x32(unsigned ks0, unsigned ks1,
                                       unsigned x0, unsigned x1,
                                       unsigned& o0, unsigned& o1) {
    unsigned ks2 = ks0 ^ ks1 ^ 0x1BD11BDAu;
    x0 += ks0; x1 += ks1;
    x0 += x1; x1 = rotl32(x1, 13); x1 ^= x0;
    x0 += x1; x1 = rotl32(x1, 15); x1 ^= x0;
    x0 += x1; x1 = rotl32(x1, 26); x1 ^= x0;
    x0 += x1; x1 = rotl32(x1, 6);  x1 ^= x0;
    x0 += ks1; x1 += ks2 + 1u;
    x0 += x1; x1 = rotl32(x1, 17); x1 ^= x0;
    x0 += x1; x1 = rotl32(x1, 29); x1 ^= x0;
    x0 += x1; x1 = rotl32(x1, 16); x1 ^= x0;
    x0 += x1; x1 = rotl32(x1, 24); x1 ^= x0;
    x0 += ks2; x1 += ks0 + 2u;
    x0 += x1; x1 = rotl32(x1, 13); x1 ^= x0;
    x0 += x1; x1 = rotl32(x1, 15); x1 ^= x0;
    x0 += x1; x1 = rotl32(x1, 26); x1 ^= x0;
    x0 += x1; x1 = rotl32(x1, 6);  x1 ^= x0;
    x0 += ks0; x1 += ks1 + 3u;
    x0 += x1; x1 = rotl32(x1, 17); x1 ^= x0;
    x0 += x1; x1 = rotl32(x1, 29); x1 ^= x0;
    x0 += x1; x1 = rotl32(x1, 16); x1 ^= x0;
    x0 += x1; x1 = rotl32(x1, 24); x1 ^= x0;
    x0 += ks1; x1 += ks2 + 4u;
    x0 += x1; x1 = rotl32(x1, 13); x1 ^= x0;
    x0 += x1; x1 = rotl32(x1, 15); x1 ^= x0;
    x0 += x1; x1 = rotl32(x1, 26); x1 ^= x0;
    x0 += x1; x1 = rotl32(x1, 6);  x1 ^= x0;
    x0 += ks2; x1 += ks0 + 5u;
    o0 = x0; o1 = x1;
}

__device__ __forceinline__ float gumbel_f(unsigned k0, unsigned k1, unsigned f) {
    unsigned o0, o1;
    tf2x32(k0, k1, 0u, f, o0, o1);
    unsigned bits = o0 ^ o1;
    float u01 = __uint_as_float((bits >> 9) | 0x3F800000u) - 1.0f;
    float u = fmaxf(TINYF, u01 * (1.0f - TINYF) + TINYF);
    return -logf(-logf(u));
}

// ---------------- encoder kernels ----------------

__global__ void k_embed(const float* __restrict__ node, const float* __restrict__ demand,
                        const float* __restrict__ Wn0, const float* __restrict__ bn0,
                        float* __restrict__ h) {
    int idx = blockIdx.x * 256 + threadIdx.x;
    if (idx >= BB * NN * HH) return;
    int r = idx >> 7, c = idx & 127;
    float v = node[r * 2] * Wn0[c] + node[r * 2 + 1] * Wn0[128 + c]
            + demand[r] * Wn0[256 + c] + bn0[c];
    h[idx] = fmaxf(v, 0.0f);
}

__global__ void k_adj(const float* __restrict__ dis, float* __restrict__ A) {
    int row = blockIdx.x;
    const float* d = dis + row * NN;
    int l = threadIdx.x;
    float v0 = (l < NN) ? -d[l] : -__builtin_inff();
    float v1 = (l + 64 < NN) ? -d[l + 64] : -__builtin_inff();
    float m = fmaxf(v0, v1);
    for (int off = 32; off > 0; off >>= 1) m = fmaxf(m, __shfl_xor(m, off));
    float e0 = (l < NN) ? expf(v0 - m) : 0.0f;
    float e1 = (l + 64 < NN) ? expf(v1 - m) : 0.0f;
    float s = e0 + e1;
    for (int off = 32; off > 0; off >>= 1) s += __shfl_xor(s, off);
    float inv = 1.0f / s;
    if (l < NN) A[row * NN + l] = e0 * inv;
    if (l + 64 < NN) A[row * NN + l + 64] = e1 * inv;
}

// out[6400x128] = h[6400x128] @ W[128x128]
__global__ void k_hw(const float* __restrict__ h, const float* __restrict__ W,
                     float* __restrict__ out) {
    __shared__ float hs[8 * 128];
    int block_row = blockIdx.x * 8;
    int tid = threadIdx.x;
    int col = tid & 127;
    int rg = tid >> 7;
    for (int i = tid; i < 8 * 128; i += 256) hs[i] = h[block_row * 128 + i];
    __syncthreads();
    float acc[4] = {0.f, 0.f, 0.f, 0.f};
    for (int k = 0; k < 128; k++) {
        float w = W[k * 128 + col];
#pragma unroll
        for (int r = 0; r < 4; r++) acc[r] += hs[(rg + 2 * r) * 128 + k] * w;
    }
#pragma unroll
    for (int r = 0; r < 4; r++)
        out[(block_row + rg + 2 * r) * 128 + col] = acc[r];
}

// out[6400x384] = h[6400x128] @ W[128x384] + bias[384]
__global__ void k_mm384(const float* __restrict__ h, const float* __restrict__ W,
                        const float* __restrict__ bias, float* __restrict__ out) {
    __shared__ float hs[8 * 128];
    int block_row = blockIdx.x * 8;
    int tid = threadIdx.x;
    int col = blockIdx.y * 128 + (tid & 127);
    int rg = tid >> 7;
    for (int i = tid; i < 8 * 128; i += 256) hs[i] = h[block_row * 128 + i];
    __syncthreads();
    float acc[4] = {0.f, 0.f, 0.f, 0.f};
    for (int k = 0; k < 128; k++) {
        float w = W[k * 384 + col];
#pragma unroll
        for (int r = 0; r < 4; r++) acc[r] += hs[(rg + 2 * r) * 128 + k] * w;
    }
    float b = bias[col];
#pragma unroll
    for (int r = 0; r < 4; r++)
        out[(block_row + rg + 2 * r) * 384 + col] = acc[r] + b;
}

__global__ void k_transpose128(const float* __restrict__ Wq, float* __restrict__ WqT) {
    int i = blockIdx.x * 256 + threadIdx.x;
    if (i >= 128 * 128) return;
    int k = i >> 7, c = i & 127;
    WqT[k * 128 + c] = Wq[c * 128 + k];
}

__global__ void k_agg(const float* __restrict__ h, const float* __restrict__ Ws,
                      const float* __restrict__ A, const float* __restrict__ hw,
                      float* __restrict__ out) {
    __shared__ float hs[4 * 128];
    __shared__ float As[4 * 100];
    int b = blockIdx.x / 25;
    int i0 = (blockIdx.x % 25) * 4;
    int tid = threadIdx.x;
    int col = tid & 127;
    int rg = tid >> 7;
    int rowbase = b * NN + i0;
    for (int idx = tid; idx < 4 * 128; idx += 256) hs[idx] = h[rowbase * 128 + idx];
    for (int idx = tid; idx < 4 * 100; idx += 256) As[idx] = A[rowbase * 100 + idx];
    __syncthreads();
    float acc0 = 0.f, acc1 = 0.f;
    for (int k = 0; k < 128; k++) {
        float w = Ws[k * 128 + col];
        acc0 += hs[rg * 128 + k] * w;
        acc1 += hs[(rg + 2) * 128 + k] * w;
    }
    const float* hwb = hw + b * NN * 128;
    for (int j = 0; j < NN; j++) {
        float v = hwb[j * 128 + col];
        acc0 += As[rg * 100 + j] * v;
        acc1 += As[(rg + 2) * 100 + j] * v;
    }
    out[(rowbase + rg) * 128 + col]     = fmaxf(acc0, 0.0f);
    out[(rowbase + rg + 2) * 128 + col] = fmaxf(acc1, 0.0f);
}

__global__ void k_predict(const float* __restrict__ dis, const float* __restrict__ We,
                          const float* __restrict__ be, const float* __restrict__ Wc,
                          const float* __restrict__ bc, float* __restrict__ out3) {
    __shared__ float sWe[128], sbe[128], sc0[128], sc1[128];
    int tid = threadIdx.x;
    if (tid < 128) {
        sWe[tid] = We[tid];
        sbe[tid] = be[tid];
        sc0[tid] = Wc[tid * 2];
        sc1[tid] = Wc[tid * 2 + 1];
    }
    __syncthreads();
    float b0 = bc[0], b1 = bc[1];
    for (int pos = blockIdx.x * 256 + tid; pos < BB * NN * NN; pos += gridDim.x * 256) {
        float d = dis[pos];
        float a0 = b0, a1 = b1;
        for (int k = 0; k < 128; k++) {
            float e = fmaxf(d * sWe[k] + sbe[k], 0.0f);
            a0 += e * sc0[k];
            a1 += e * sc1[k];
        }
        float m = fmaxf(a0, a1);
        float p0 = expf(a0 - m), p1 = expf(a1 - m);
        float inv = 1.0f / (p0 + p1);
        out3[pos * 2]     = p0 * inv;
        out3[pos * 2 + 1] = p1 * inv;
    }
}

__global__ void k_zero(float* __restrict__ p, int n) {
    int i = blockIdx.x * 256 + threadIdx.x;
    if (i < n) p[i] = 0.0f;
}

// ---------------- decoder v6: decode5 + FORCED 256-VGPR allocation ----------------
// decode5 failed because __launch_bounds__(512,2) only sets a MIN waves/EU; the
// allocator chose 4 waves/EU (128 VGPR) and spilled the 192-float weight tiles
// (WRITE_SIZE 36 MB, VGPR_Count 128). amdgpu_waves_per_eu(2,2) pins max 2
// waves/EU -> 256 VGPR budget; 192 persistent + ~40 working fits.
__global__
__attribute__((amdgpu_flat_work_group_size(512, 512), amdgpu_waves_per_eu(2, 2)))
void k_decode6(
    const float* __restrict__ P0,       // [6400, 384]  x@Wih0 + bih0
    const float* __restrict__ Z,        // [6400, 128]  x@Wq^T
    const float* __restrict__ dis,
    const float* __restrict__ Wih,      // [2,128,384]
    const float* __restrict__ Whh,      // [2,128,384]
    const float* __restrict__ bih,
    const float* __restrict__ bhh,
    float* __restrict__ out) {
    __shared__ float Zs[NN * 132];          // 52.8 KB
    __shared__ float h0s[2 * 132], h1s[2 * 132];
    __shared__ float gi0s[2 * 384];
    __shared__ float pgA[8 * 2 * 392];      // gh0 partials; reused for gi1 after phase B
    __shared__ float pgB[8 * 2 * 392];      // gh1 partials (live until phase D)
    __shared__ float sbhh0[T3], sbih1[T3], sbhh1[T3];
    __shared__ float pl[2 * 2 * 100];       // [m][ks][n]
    __shared__ float gum[128];
    __shared__ int s_ind2[2];

    const int tid = threadIdx.x;
    const int b = blockIdx.x;
    const int kg = tid >> 6;            // 0..7 -> k0 = kg*16
    const int jg = tid & 63;            // 0..63 -> j0 = jg*6
    const int k0 = kg * 16, j0 = jg * 6;

    const float* __restrict__ Wih1 = Wih + 128 * T3;

    // ---- load register weight tiles (Whh0, Whh1): 192 VGPRs persistent ----
    float wA[16][6], wB[16][6];
    {
        const float* WAp = Whh + (size_t)k0 * T3 + j0;
        const float* WBp = Whh + 128 * T3 + (size_t)k0 * T3 + j0;
#pragma unroll
        for (int k = 0; k < 16; k++) {
#pragma unroll
            for (int q = 0; q < 3; q++) {
                float2 a = *(const float2*)(WAp + (size_t)k * T3 + 2 * q);
                wA[k][2 * q] = a.x; wA[k][2 * q + 1] = a.y;
                float2 c = *(const float2*)(WBp + (size_t)k * T3 + 2 * q);
                wB[k][2 * q] = c.x; wB[k][2 * q + 1] = c.y;
            }
        }
    }

    // ---- static staging ----
    for (int i4 = tid; i4 < NN * 32; i4 += 512) {
        int r = i4 >> 5, c4 = (i4 & 31) * 4;
        *(float4*)&Zs[r * 132 + c4] = *(const float4*)&Z[(b * NN + r) * 128 + c4];
    }
    if (tid < T3) {
        sbhh0[tid] = bhh[tid];
        sbih1[tid] = bih[T3 + tid];
        sbhh1[tid] = bhh[T3 + tid];
    }
    if (tid < 256) {
        int m = tid >> 7, i = tid & 127;
        h0s[m * 132 + i] = 0.0f;
        h1s[m * 132 + i] = 0.0f;
    }
    if (tid == 0) { s_ind2[0] = 0; s_ind2[1] = 0; }

    unsigned kk0, kk1;
    tf2x32(0u, 42u, 0u, 0u, kk0, kk1);   // k1 of split(key(42))

    int lastm = 0;       // tracked by tid<128 (selection threads)
    float dist = 0.0f;
    __syncthreads();

    for (int t = 0; t < NN - 1; t++) {
        // ---- RNG chain advance (uniform, all threads) ----
        unsigned sk0, sk1, nkA, nkB;
        tf2x32(kk0, kk1, 0u, 1u, sk0, sk1);
        tf2x32(kk0, kk1, 0u, 0u, nkA, nkB);
        kk0 = nkA; kk1 = nkB;

        // ---- gi0 prefetch (row of P0 per mode) into registers ----
        float pf0 = 0.f, pf1 = 0.f;
        int pf_m = 0, pf_j = 0;
        if (tid < 384) {
            pf_m = (tid >= 192);
            pf_j = (tid - pf_m * 192) * 2;
            float2 g2 = *(const float2*)&P0[(size_t)(b * NN + s_ind2[pf_m]) * T3 + pf_j];
            pf0 = g2.x; pf1 = g2.y;
        }

        // ===== phase A: gh0 (reg wA) and gh1 (reg wB) partials =====
        {
            float acc0[6], acc1[6];
#pragma unroll
            for (int j = 0; j < 6; j++) { acc0[j] = 0.f; acc1[j] = 0.f; }
#pragma unroll
            for (int q = 0; q < 4; q++) {
                float4 ha = *(const float4*)&h0s[k0 + 4 * q];
                float4 hb = *(const float4*)&h0s[132 + k0 + 4 * q];
#pragma unroll
                for (int j = 0; j < 6; j++) {
                    acc0[j] += wA[4 * q + 0][j] * ha.x + wA[4 * q + 1][j] * ha.y
                             + wA[4 * q + 2][j] * ha.z + wA[4 * q + 3][j] * ha.w;
                    acc1[j] += wA[4 * q + 0][j] * hb.x + wA[4 * q + 1][j] * hb.y
                             + wA[4 * q + 2][j] * hb.z + wA[4 * q + 3][j] * hb.w;
                }
            }
#pragma unroll
            for (int q = 0; q < 3; q++) {
                float2 o0; o0.x = acc0[2 * q]; o0.y = acc0[2 * q + 1];
                *(float2*)&pgA[(kg * 2 + 0) * 392 + j0 + 2 * q] = o0;
                float2 o1; o1.x = acc1[2 * q]; o1.y = acc1[2 * q + 1];
                *(float2*)&pgA[(kg * 2 + 1) * 392 + j0 + 2 * q] = o1;
            }
        }
        {
            float acc0[6], acc1[6];
#pragma unroll
            for (int j = 0; j < 6; j++) { acc0[j] = 0.f; acc1[j] = 0.f; }
#pragma unroll
            for (int q = 0; q < 4; q++) {
                float4 ha = *(const float4*)&h1s[k0 + 4 * q];
                float4 hb = *(const float4*)&h1s[132 + k0 + 4 * q];
#pragma unroll
                for (int j = 0; j < 6; j++) {
                    acc0[j] += wB[4 * q + 0][j] * ha.x + wB[4 * q + 1][j] * ha.y
                             + wB[4 * q + 2][j] * ha.z + wB[4 * q + 3][j] * ha.w;
                    acc1[j] += wB[4 * q + 0][j] * hb.x + wB[4 * q + 1][j] * hb.y
                             + wB[4 * q + 2][j] * hb.z + wB[4 * q + 3][j] * hb.w;
                }
            }
#pragma unroll
            for (int q = 0; q < 3; q++) {
                float2 o0; o0.x = acc0[2 * q]; o0.y = acc0[2 * q + 1];
                *(float2*)&pgB[(kg * 2 + 0) * 392 + j0 + 2 * q] = o0;
                float2 o1; o1.x = acc1[2 * q]; o1.y = acc1[2 * q + 1];
                *(float2*)&pgB[(kg * 2 + 1) * 392 + j0 + 2 * q] = o1;
            }
        }
        if (tid < 384) {
            gi0s[pf_m * 384 + pf_j] = pf0;
            gi0s[pf_m * 384 + pf_j + 1] = pf1;
        }
        __syncthreads();

        // ===== phase B: h0 update (256 thr) =====
        if (tid < 256) {
            int m = tid >> 7, i = tid & 127;
            float ghr = sbhh0[i], ghz = sbhh0[i + 128], ghn = sbhh0[i + 256];
#pragma unroll
            for (int g = 0; g < 8; g++) {
                int pb = (g * 2 + m) * 392;
                ghr += pgA[pb + i];
                ghz += pgA[pb + i + 128];
                ghn += pgA[pb + i + 256];
            }
            float rr = 1.0f / (1.0f + expf(-(gi0s[m * 384 + i] + ghr)));
            float zz = 1.0f / (1.0f + expf(-(gi0s[m * 384 + i + 128] + ghz)));
            float nn = tanhf(gi0s[m * 384 + i + 256] + rr * ghn);
            h0s[m * 132 + i] = (1.0f - zz) * nn + zz * h0s[m * 132 + i];
        }
        __syncthreads();

        // ===== phase C: gi1 partials (streamed Wih1, all 512 thr) =====
        {
            float acc0[6], acc1[6];
#pragma unroll
            for (int j = 0; j < 6; j++) { acc0[j] = 0.f; acc1[j] = 0.f; }
#pragma unroll
            for (int q = 0; q < 4; q++) {
                float4 ha = *(const float4*)&h0s[k0 + 4 * q];
                float4 hb = *(const float4*)&h0s[132 + k0 + 4 * q];
#pragma unroll
                for (int kk2 = 0; kk2 < 4; kk2++) {
                    const float* wp = Wih1 + (size_t)(k0 + 4 * q + kk2) * T3 + j0;
                    float2 w01 = *(const float2*)(wp);
                    float2 w23 = *(const float2*)(wp + 2);
                    float2 w45 = *(const float2*)(wp + 4);
                    float hx = (kk2 == 0) ? ha.x : (kk2 == 1) ? ha.y : (kk2 == 2) ? ha.z : ha.w;
                    float hy = (kk2 == 0) ? hb.x : (kk2 == 1) ? hb.y : (kk2 == 2) ? hb.z : hb.w;
                    acc0[0] += w01.x * hx; acc0[1] += w01.y * hx;
                    acc0[2] += w23.x * hx; acc0[3] += w23.y * hx;
                    acc0[4] += w45.x * hx; acc0[5] += w45.y * hx;
                    acc1[0] += w01.x * hy; acc1[1] += w01.y * hy;
                    acc1[2] += w23.x * hy; acc1[3] += w23.y * hy;
                    acc1[4] += w45.x * hy; acc1[5] += w45.y * hy;
                }
            }
#pragma unroll
            for (int q = 0; q < 3; q++) {
                float2 o0; o0.x = acc0[2 * q]; o0.y = acc0[2 * q + 1];
                *(float2*)&pgA[(kg * 2 + 0) * 392 + j0 + 2 * q] = o0;
                float2 o1; o1.x = acc1[2 * q]; o1.y = acc1[2 * q + 1];
                *(float2*)&pgA[(kg * 2 + 1) * 392 + j0 + 2 * q] = o1;
            }
        }
        __syncthreads();

        // ===== phase D: h1 update (256 thr) =====
        if (tid < 256) {
            int m = tid >> 7, i = tid & 127;
            float gir = sbih1[i], giz = sbih1[i + 128], gin = sbih1[i + 256];
            float ghr = sbhh1[i], ghz = sbhh1[i + 128], ghn = sbhh1[i + 256];
#pragma unroll
            for (int g = 0; g < 8; g++) {
                int pa = (g * 2 + m) * 392;
                gir += pgA[pa + i];
                giz += pgA[pa + i + 128];
                gin += pgA[pa + i + 256];
                ghr += pgB[pa + i];
                ghz += pgB[pa + i + 128];
                ghn += pgB[pa + i + 256];
            }
            float rr = 1.0f / (1.0f + expf(-(gir + ghr)));
            float zz = 1.0f / (1.0f + expf(-(giz + ghz)));
            float nn = tanhf(gin + rr * ghn);
            h1s[m * 132 + i] = (1.0f - zz) * nn + zz * h1s[m * 132 + i];
        }
        __syncthreads();

        // ===== phase E: logits partials (200 thr) + gumbel (thr 256..355) =====
        if (tid < 200) {
            int ks = tid / 100, n = tid - ks * 100;
            int kk0p = ks * 64;
            const float* Zp = &Zs[n * 132 + kk0p];
            const float* hp = &h1s[kk0p];
            float a0 = 0.f, a1 = 0.f;
#pragma unroll 4
            for (int q = 0; q < 16; q++) {
                float4 z4 = *(const float4*)(Zp + 4 * q);
                float4 hA = *(const float4*)(hp + 4 * q);
                float4 hB = *(const float4*)(hp + 132 + 4 * q);
                a0 += hA.x * z4.x; a0 += hA.y * z4.y; a0 += hA.z * z4.z; a0 += hA.w * z4.w;
                a1 += hB.x * z4.x; a1 += hB.y * z4.y; a1 += hB.z * z4.z; a1 += hB.w * z4.w;
            }
            pl[(0 * 2 + ks) * 100 + n] = a0;
            pl[(1 * 2 + ks) * 100 + n] = a1;
        } else if (tid >= 256 && tid < 356) {
            int u = tid - 256;
            gum[u] = gumbel_f(sk0, sk1, (unsigned)(b * NN + u));
        }
        __syncthreads();

        // ===== phase F: softmax stats + selection (wave0: sample, wave1: greedy) =====
        if (tid < 128) {
            const int m = tid >> 6, lane = tid & 63;
            float v0, v1 = -__builtin_inff();
            v0 = (pl[(m * 2 + 0) * 100 + lane] + pl[(m * 2 + 1) * 100 + lane]) * SCALEF;
            if (lane + 64 < NN)
                v1 = (pl[(m * 2 + 0) * 100 + lane + 64] + pl[(m * 2 + 1) * 100 + lane + 64]) * SCALEF;
            float mx = fmaxf(v0, v1);
            for (int off = 32; off > 0; off >>= 1) mx = fmaxf(mx, __shfl_xor(mx, off));
            float e = expf(v0 - mx) + ((lane + 64 < NN) ? expf(v1 - mx) : 0.0f);
            for (int off = 32; off > 0; off >>= 1) e += __shfl_xor(e, off);
            float a0 = v0, a1 = v1;
            if (m == 0) {
                a0 += gum[lane];
                if (lane + 64 < NN) a1 += gum[lane + 64];
            }
            float bv; int bi;
            if (a1 > a0) { bv = a1; bi = lane + 64; } else { bv = a0; bi = lane; }
            for (int off = 32; off > 0; off >>= 1) {
                float ov = __shfl_xor(bv, off);
                int   oi = __shfl_xor(bi, off);
                if (ov > bv || (ov == bv && oi < bi)) { bv = ov; bi = oi; }
            }
            int ind = bi;
            float la = __shfl(v0, ind & 63);
            float lb = __shfl(v1, ind & 63);
            float lv = (ind < 64) ? la : lb;
            if (lane == 0) {
                if (m == 0) out[O0 + b * (NN - 1) + t] = lv - mx - logf(e);
                else        out[O4 + (size_t)b * NN * NN + lastm * NN + ind] = 1.0f;
                s_ind2[m] = ind;
            }
            dist += dis[b * NN * NN + lastm * NN + ind];
            lastm = ind;
        }
        __syncthreads();
    }

    if (tid == 0)  out[O1 + b] = dist;
    if (tid == 64) out[O2 + b] = dist;
}

// ---------------- fallback decoder (round-2 verified, small ws) ----------------
__global__ __launch_bounds__(768) void k_decode2(
    const float* __restrict__ P0, const float* __restrict__ Z,
    const float* __restrict__ dis,
    const float* __restrict__ Wih, const float* __restrict__ Whh,
    const float* __restrict__ bih, const float* __restrict__ bhh,
    float* __restrict__ out) {
    __shared__ float Zs[NN * 129];
    __shared__ float h0s[128], h1s[128];
    __shared__ float gi0s[T3];
    __shared__ float pg0[2 * T3];
    __shared__ float gi1s[T3], gh1s[T3];
    __shared__ float sbhh0[T3], sbih1[T3], sbhh1[T3];
    __shared__ float plx[4 * NN];
    __shared__ float logits[NN];
    __shared__ float s_m, s_s;
    __shared__ int s_ind;

    const int tid = threadIdx.x;
    const int b = blockIdx.x >> 1;
    const int greedy = blockIdx.x & 1;

    const float* Whh0 = Whh;
    const float* Wih1 = Wih + 128 * T3;
    const float* Whh1 = Whh + 128 * T3;

    for (int idx = tid; idx < NN * 128; idx += 768) {
        int r = idx >> 7, c = idx & 127;
        Zs[r * 129 + c] = Z[(b * NN + r) * 128 + c];
    }
    if (tid < T3) {
        sbhh0[tid] = bhh[tid];
        sbih1[tid] = bih[T3 + tid];
        sbhh1[tid] = bhh[T3 + tid];
    }
    if (tid < 128) { h0s[tid] = 0.0f; h1s[tid] = 0.0f; }

    unsigned kk0, kk1;
    tf2x32(0u, 42u, 0u, 0u, kk0, kk1);

    int last = 0;
    float dist = 0.0f;
    __syncthreads();

    for (int t = 0; t < NN - 1; t++) {
        unsigned sk0, sk1, nk0, nk1;
        tf2x32(kk0, kk1, 0u, 1u, sk0, sk1);
        tf2x32(kk0, kk1, 0u, 0u, nk0, nk1);
        kk0 = nk0; kk1 = nk1;

        {
            const float* P0row = P0 + (size_t)(b * NN + last) * T3;
            if (tid < T3) {
                int j = tid;
                float acc = 0.0f;
                for (int k = 0; k < 64; k++) acc += h0s[k] * Whh0[k * T3 + j];
                pg0[j] = acc;
                gi0s[j] = P0row[j];
            } else {
                int j = tid - T3;
                float acc = 0.0f;
                for (int k = 64; k < 128; k++) acc += h0s[k] * Whh0[k * T3 + j];
                pg0[T3 + j] = acc;
            }
        }
        __syncthreads();
        if (tid < 128) {
            float ghr = pg0[tid] + pg0[T3 + tid] + sbhh0[tid];
            float ghz = pg0[tid + 128] + pg0[T3 + tid + 128] + sbhh0[tid + 128];
            float ghn = pg0[tid + 256] + pg0[T3 + tid + 256] + sbhh0[tid + 256];
            float r = 1.0f / (1.0f + expf(-(gi0s[tid] + ghr)));
            float z = 1.0f / (1.0f + expf(-(gi0s[tid + 128] + ghz)));
            float n = tanhf(gi0s[tid + 256] + r * ghn);
            h0s[tid] = (1.0f - z) * n + z * h0s[tid];
        }
        __syncthreads();
        if (tid < T3) {
            int j = tid;
            float acc = sbih1[j];
            for (int k = 0; k < 128; k++) acc += h0s[k] * Wih1[k * T3 + j];
            gi1s[j] = acc;
        } else {
            int j = tid - T3;
            float acc = sbhh1[j];
            for (int k = 0; k < 128; k++) acc += h1s[k] * Whh1[k * T3 + j];
            gh1s[j] = acc;
        }
        __syncthreads();
        if (tid < 128) {
            float r = 1.0f / (1.0f + expf(-(gi1s[tid] + gh1s[tid])));
            float z = 1.0f / (1.0f + expf(-(gi1s[tid + 128] + gh1s[tid + 128])));
            float n = tanhf(gi1s[tid + 256] + r * gh1s[tid + 256]);
            h1s[tid] = (1.0f - z) * n + z * h1s[tid];
        }
        __syncthreads();
        if (tid < 400) {
            int n = tid % 100, p = tid / 100;
            int k0 = p * 32;
            float acc = 0.0f;
            for (int kk = 0; kk < 32; kk++) acc += h1s[k0 + kk] * Zs[n * 129 + k0 + kk];
            plx[p * 100 + n] = acc;
        }
        __syncthreads();
        if (tid < 64) {
            float v0 = -__builtin_inff(), v1 = -__builtin_inff();
            {
                int n = tid;
                v0 = (plx[n] + plx[100 + n] + plx[200 + n] + plx[300 + n]) * SCALEF;
                logits[n] = v0;
            }
            if (tid + 64 < NN) {
                int n = tid + 64;
                v1 = (plx[n] + plx[100 + n] + plx[200 + n] + plx[300 + n]) * SCALEF;
                logits[n] = v1;
            }
            float m = fmaxf(v0, v1);
            for (int off = 32; off > 0; off >>= 1) m = fmaxf(m, __shfl_xor(m, off));
            float e = expf(v0 - m) + ((tid + 64 < NN) ? expf(v1 - m) : 0.0f);
            for (int off = 32; off > 0; off >>= 1) e += __shfl_xor(e, off);
            float a0 = v0, a1 = v1;
            if (!greedy) {
                a0 = v0 + gumbel_f(sk0, sk1, (unsigned)(b * NN + tid));
                if (tid + 64 < NN) a1 = v1 + gumbel_f(sk0, sk1, (unsigned)(b * NN + tid + 64));
            }
            float bv; int bi;
            if (a1 > a0) { bv = a1; bi = tid + 64; } else { bv = a0; bi = tid; }
            for (int off = 32; off > 0; off >>= 1) {
                float ov = __shfl_xor(bv, off);
                int   oi = __shfl_xor(bi, off);
                if (ov > bv || (ov == bv && oi < bi)) { bv = ov; bi = oi; }
            }
            if (tid == 0) { s_m = m; s_s = e; s_ind = bi; }
        }
        __syncthreads();
        int ind = s_ind;
        if (tid == 0) {
            if (!greedy) out[O0 + b * (NN - 1) + t] = logits[ind] - s_m - logf(s_s);
            dist += dis[b * NN * NN + last * NN + ind];
            if (greedy) out[O4 + b * NN * NN + last * NN + ind] = 1.0f;
        }
        last = ind;
        __syncthreads();
    }
    if (tid == 0) {
        if (!greedy) out[O1 + b] = dist;
        else         out[O2 + b] = dist;
    }
}

// ---------------- host launcher ----------------
extern "C" void kernel_launch(void* const* d_in, const int* in_sizes, int n_in,
                              void* d_out, int out_size, void* d_ws, size_t ws_size,
                              hipStream_t stream) {
    (void)in_sizes; (void)n_in; (void)out_size;
    const float* node   = (const float*)d_in[0];
    const float* demand = (const float*)d_in[1];
    const float* dis    = (const float*)d_in[2];
    const float* Wn0    = (const float*)d_in[3];
    const float* bn0    = (const float*)d_in[4];
    const float* Ws     = (const float*)d_in[5];
    const float* Wngh   = (const float*)d_in[6];
    const float* We     = (const float*)d_in[7];
    const float* be     = (const float*)d_in[8];
    const float* Wih    = (const float*)d_in[9];
    const float* Whh    = (const float*)d_in[10];
    const float* bih    = (const float*)d_in[11];
    const float* bhh    = (const float*)d_in[12];
    const float* Wq     = (const float*)d_in[13];
    const float* Wc     = (const float*)d_in[14];
    const float* bc     = (const float*)d_in[15];
    float* out = (float*)d_out;
    float* ws  = (float*)d_ws;

    float* hA  = ws;
    float* hB  = ws + 819200;
    float* hw  = ws + 1638400;      // hw during encoder; Z after
    float* A   = ws + 2457600;
    float* P0  = ws + 2457600;      // overlays A after encoder
    float* WqT = ws + 4915200;
    const size_t need_bytes = (size_t)4931584 * 4;
    const bool big_ws = ws_size >= need_bytes;

    hipLaunchKernelGGL(k_embed, dim3(3200), dim3(256), 0, stream, node, demand, Wn0, bn0, hA);
    hipLaunchKernelGGL(k_adj, dim3(6400), dim3(64), 0, stream, dis, A);

    float* cur = hA;
    float* nxt = hB;
    for (int l = 0; l < 3; l++) {
        hipLaunchKernelGGL(k_hw, dim3(800), dim3(256), 0, stream, cur, Wngh + l * 16384, hw);
        hipLaunchKernelGGL(k_agg, dim3(1600), dim3(256), 0, stream, cur, Ws + l * 16384, A, hw, nxt);
        float* tswap = cur; cur = nxt; nxt = tswap;
    }

    hipLaunchKernelGGL(k_predict, dim3(2500), dim3(256), 0, stream, dis, We, be, Wc, bc, out + O3);
    hipLaunchKernelGGL(k_zero, dim3(2500), dim3(256), 0, stream, out + O4, BB * NN * NN);

    hipLaunchKernelGGL(k_transpose128, dim3(64), dim3(256), 0, stream, Wq, WqT);
    hipLaunchKernelGGL(k_hw, dim3(800), dim3(256), 0, stream, cur, WqT, hw);   // Z
    hipLaunchKernelGGL(k_mm384, dim3(800, 3), dim3(256), 0, stream, cur, Wih, bih, P0);
    if (big_ws) {
        hipLaunchKernelGGL(k_decode6, dim3(64), dim3(512), 0, stream,
                           P0, hw, dis, Wih, Whh, bih, bhh, out);
    } else {
        hipLaunchKernelGGL(k_decode2, dim3(128), dim3(768), 0, stream,
                           P0, hw, dis, Wih, Whh, bih, bhh, out);
    }
}